// Round 1
// baseline (7580.074 us; speedup 1.0000x reference)
//
#include <hip/hip_runtime.h>

// Deformable KPN pipeline, fp32 direct implementation.
// Shapes: B=4, D=5(frames), C=3, H=W=256, S=27 samples, GROUPS=3.
//
// Pipeline:
//  1. f1      = relu(conv3x3(data[B,15,H,W], enc_w1))       -> ws A   (64 MB)
//  2. feature = relu(conv3x3(f1, enc_w2))       128ch       -> ws B   (128 MB)
//  3. offsets = conv3x3(feature, off_w)          81ch       -> d_out samples region
//  4. samples = trilinear(data, offsets)  IN-PLACE in d_out samples region
//     (each thread reads offset channels s*3+{0,1,2} and writes sample
//      channels s*3+{0,1,2} at the same pixel -> same addresses, no race)
//  5. h1      = relu(conv3x3([data|feature|samples] 224ch, wc_w1)) -> ws A
//  6. h2      = relu(conv3x3(h1, wc_w2))                           -> ws B (front)
//  7. weights = conv3x3(h2, wc_w3) 27ch                            -> ws B + 64MB
//  8. res_i/out combine                                            -> d_out

#define HH 256
#define WW 256

constexpr int TILE_W = 32, TILE_H = 8;      // 256 px per block, 1 px/thread
constexpr int LDS_W = 34, LDS_H = 10;       // +1 halo each side
constexpr int CH_CHUNK = 16;                // input channels staged per pass
constexpr int CO_CHUNK = 16;                // output channels per block (acc regs)
constexpr int LDS_PER_CH = LDS_W * LDS_H;   // 340

// Generic 3x3 SAME conv, stride 1. Input channels come from up to 3
// concatenated sources (for the weight-conv's [net_feed|feature|samples]).
template <bool RELU>
__global__ __launch_bounds__(256) void conv3x3_kern(
    const float* __restrict__ s0, int c0,
    const float* __restrict__ s1, int c1,
    const float* __restrict__ s2, int c2,
    const float* __restrict__ Wt, const float* __restrict__ bias,
    int Cout, float* __restrict__ dst)
{
    const int Cin = c0 + c1 + c2;
    __shared__ float lds[CH_CHUNK * LDS_PER_CH]; // 5440 floats = 21.25 KB

    const int tid = threadIdx.x;
    const int tile = blockIdx.x;          // 8 x 32 tiles
    const int x0 = (tile & 7) * TILE_W;
    const int y0 = (tile >> 3) * TILE_H;
    const int b = blockIdx.y;
    const int cout_base = blockIdx.z * CO_CHUNK;

    const int px = tid & 31;
    const int py = tid >> 5;

    float acc[CO_CHUNK];
#pragma unroll
    for (int i = 0; i < CO_CHUNK; ++i) acc[i] = 0.f;

    for (int cin_base = 0; cin_base < Cin; cin_base += CH_CHUNK) {
        __syncthreads();
        // ---- stage CH_CHUNK input channels (with halo, zero-padded) ----
        for (int idx = tid; idx < CH_CHUNK * LDS_PER_CH; idx += 256) {
            int ch  = idx / LDS_PER_CH;
            int rem = idx - ch * LDS_PER_CH;
            int ly  = rem / LDS_W;
            int lx  = rem - ly * LDS_W;
            int gc  = cin_base + ch;
            int gy  = y0 - 1 + ly;
            int gx  = x0 - 1 + lx;
            float v = 0.f;
            if (gc < Cin && (unsigned)gy < HH && (unsigned)gx < WW) {
                const float* p; int cs, cc;
                if (gc < c0)           { p = s0; cs = c0; cc = gc; }
                else if (gc < c0 + c1) { p = s1; cs = c1; cc = gc - c0; }
                else                   { p = s2; cs = c2; cc = gc - c0 - c1; }
                v = p[((b * cs + cc) << 16) + (gy << 8) + gx];
            }
            lds[idx] = v;
        }
        __syncthreads();

        const int nci = min(CH_CHUNK, Cin - cin_base);
        for (int ci = 0; ci < nci; ++ci) {
            float patch[9];
            const float* lp = &lds[ci * LDS_PER_CH + py * LDS_W + px];
#pragma unroll
            for (int dy = 0; dy < 3; ++dy)
#pragma unroll
                for (int dx = 0; dx < 3; ++dx)
                    patch[dy * 3 + dx] = lp[dy * LDS_W + dx];

            const int gci = cin_base + ci;
#pragma unroll
            for (int co = 0; co < CO_CHUNK; ++co) {
                if (cout_base + co < Cout) {
                    // uniform address -> scalar loads feeding v_fmac SGPR src
                    const float* wp = Wt + ((cout_base + co) * Cin + gci) * 9;
#pragma unroll
                    for (int t = 0; t < 9; ++t)
                        acc[co] = fmaf(wp[t], patch[t], acc[co]);
                }
            }
        }
    }

    const int y = y0 + py, x = x0 + px;
#pragma unroll
    for (int co = 0; co < CO_CHUNK; ++co) {
        int coo = cout_base + co;
        if (coo < Cout) {
            float r = acc[co] + bias[coo];
            if (RELU) r = fmaxf(r, 0.f);
            dst[((b * Cout + coo) << 16) + (y << 8) + x] = r;
        }
    }
}

// Trilinear sampling, in-place over the offsets buffer (offset channels
// s*3+{0,1,2} become sample channels s*3+{0,1,2} for c=0..2).
__global__ __launch_bounds__(256) void trilinear_kern(
    const float* __restrict__ data, float* __restrict__ smp)
{
    int i = blockIdx.x * 256 + threadIdx.x;   // B*S*H*W = 7,077,888 exactly
    int p = i & 65535;
    int hs = i >> 16;                          // b*27 + s
    int s = hs % 27;
    int b = hs / 27;
    int y = p >> 8, x = p & 255;

    float o0 = smp[((b * 81 + s * 3 + 0) << 16) + p];
    float o1 = smp[((b * 81 + s * 3 + 1) << 16) + p];
    float o2 = smp[((b * 81 + s * 3 + 2) << 16) + p];

    float kd = (float)(s / 9 - 1);
    float kh = (float)((s / 3) % 3 - 1);
    float kw = (float)(s % 3 - 1);

    float pd = 2.0f + kd + o0;                 // center = (D-1)/2 = 2
    float ph = (float)y + kh + o1;
    float pw = (float)x + kw + o2;
    pd = fminf(fmaxf(pd, 0.f), 4.f);
    ph = fminf(fmaxf(ph, 0.f), 255.f);
    pw = fminf(fmaxf(pw, 0.f), 255.f);

    float d0 = floorf(pd), h0 = floorf(ph), w0 = floorf(pw);
    float fd = pd - d0, fh = ph - h0, fw = pw - w0;
    int d0i = (int)d0, h0i = (int)h0, w0i = (int)w0;
    int d1i = min(d0i + 1, 4), h1i = min(h0i + 1, 255), w1i = min(w0i + 1, 255);

#pragma unroll
    for (int c = 0; c < 3; ++c) {
        auto ld = [&](int di, int hi, int wi) {
            return data[(((b * 5 + di) * 3 + c) << 16) + (hi << 8) + wi];
        };
        float v000 = ld(d0i, h0i, w0i), v001 = ld(d0i, h0i, w1i);
        float v010 = ld(d0i, h1i, w0i), v011 = ld(d0i, h1i, w1i);
        float v100 = ld(d1i, h0i, w0i), v101 = ld(d1i, h0i, w1i);
        float v110 = ld(d1i, h1i, w0i), v111 = ld(d1i, h1i, w1i);
        float r0 = (v000 * (1.f - fw) + v001 * fw) * (1.f - fh)
                 + (v010 * (1.f - fw) + v011 * fw) * fh;
        float r1 = (v100 * (1.f - fw) + v101 * fw) * (1.f - fh)
                 + (v110 * (1.f - fw) + v111 * fw) * fh;
        float r = r0 * (1.f - fd) + r1 * fd;
        smp[((b * 81 + s * 3 + c) << 16) + p] = r;
    }
}

// res_i[b,g,c] = 3 * sum_k samples[b,g*9+k,c] * weights[b,g*9+k]
// out[b,c] = sum_g res_i[b,g,c] / 3
__global__ __launch_bounds__(256) void combine_kern(
    const float* __restrict__ smp, const float* __restrict__ wt,
    float* __restrict__ res_i, float* __restrict__ outp)
{
    int i = blockIdx.x * 256 + threadIdx.x;   // B*H*W = 262,144
    int p = i & 65535;
    int b = i >> 16;
    float ov[3] = {0.f, 0.f, 0.f};
#pragma unroll
    for (int g = 0; g < 3; ++g) {
        float r[3] = {0.f, 0.f, 0.f};
#pragma unroll
        for (int k = 0; k < 9; ++k) {
            int s = g * 9 + k;
            float w = wt[((b * 27 + s) << 16) + p];
#pragma unroll
            for (int c = 0; c < 3; ++c)
                r[c] = fmaf(smp[(((b * 27 + s) * 3 + c) << 16) + p], w, r[c]);
        }
#pragma unroll
        for (int c = 0; c < 3; ++c) {
            res_i[(((b * 3 + g) * 3 + c) << 16) + p] = 3.f * r[c];
            ov[c] += r[c];
        }
    }
#pragma unroll
    for (int c = 0; c < 3; ++c)
        outp[((b * 3 + c) << 16) + p] = ov[c];
}

extern "C" void kernel_launch(void* const* d_in, const int* in_sizes, int n_in,
                              void* d_out, int out_size, void* d_ws, size_t ws_size,
                              hipStream_t stream)
{
    const float* data   = (const float*)d_in[0];   // [4,5,3,256,256] == [4,15,256,256]
    const float* enc_w1 = (const float*)d_in[1];
    const float* enc_b1 = (const float*)d_in[2];
    const float* enc_w2 = (const float*)d_in[3];
    const float* enc_b2 = (const float*)d_in[4];
    const float* off_w  = (const float*)d_in[5];
    const float* off_b  = (const float*)d_in[6];
    const float* wc_w1  = (const float*)d_in[7];
    const float* wc_b1  = (const float*)d_in[8];
    const float* wc_w2  = (const float*)d_in[9];
    const float* wc_b2  = (const float*)d_in[10];
    const float* wc_w3  = (const float*)d_in[11];
    const float* wc_b3  = (const float*)d_in[12];

    float* dout  = (float*)d_out;
    float* res_i = dout;                  // [4,3,3,256,256]  2,359,296
    float* outp  = dout + 2359296;        // [4,3,256,256]      786,432
    float* smp   = dout + 3145728;        // [4,81,256,256]  21,233,664 (offsets -> samples)

    float* A  = (float*)d_ws;             // 16,777,216 floats (f1, later h1)
    float* B  = A + 16777216;             // 33,554,432 floats (feature; later h2+weights)
    float* h2 = B;
    float* wts = B + 16777216;

    dim3 blk(256);

    // 1. f1 = relu(conv 15->64) -> A
    conv3x3_kern<true><<<dim3(256, 4, 4), blk, 0, stream>>>(
        data, 15, data, 0, data, 0, enc_w1, enc_b1, 64, A);
    // 2. feature = relu(conv 64->128) -> B
    conv3x3_kern<true><<<dim3(256, 4, 8), blk, 0, stream>>>(
        A, 64, A, 0, A, 0, enc_w2, enc_b2, 128, B);
    // 3. offsets = conv 128->81 -> smp (d_out samples region)
    conv3x3_kern<false><<<dim3(256, 4, 6), blk, 0, stream>>>(
        B, 128, B, 0, B, 0, off_w, off_b, 81, smp);
    // 4. samples = trilinear(data, offsets), in place
    trilinear_kern<<<27648, blk, 0, stream>>>(data, smp);
    // 5. h1 = relu(conv [15|128|81]=224 -> 64) -> A
    conv3x3_kern<true><<<dim3(256, 4, 4), blk, 0, stream>>>(
        data, 15, B, 128, smp, 81, wc_w1, wc_b1, 64, A);
    // 6. h2 = relu(conv 64->64) -> B front
    conv3x3_kern<true><<<dim3(256, 4, 4), blk, 0, stream>>>(
        A, 64, A, 0, A, 0, wc_w2, wc_b2, 64, h2);
    // 7. weights = conv 64->27 -> B + 64MB
    conv3x3_kern<false><<<dim3(256, 4, 2), blk, 0, stream>>>(
        h2, 64, h2, 0, h2, 0, wc_w3, wc_b3, 27, wts);
    // 8. combine -> res_i, out
    combine_kern<<<1024, blk, 0, stream>>>(smp, wts, res_i, outp);
}

// Round 3
// 819.573 us; speedup vs baseline: 9.2488x; 9.2488x over previous
//
#include <hip/hip_runtime.h>

// Deformable KPN, bf16 MFMA implicit-GEMM pipeline.
// B=4, D=5, C=3, H=W=256, S=27, GROUPS=3.
//
// Activations: NHWC bf16. concat buffer [B][HW][232]: ch0-14 data, ch15 pad,
// ch16-143 feature, ch144-224 offsets->samples (in-place), 225-231 pad.
// Convs: 9-tap accumulated 1x1 GEMMs, mfma_f32_16x16x32_bf16, fp32 accum.
// Weights pre-packed per launch into A-fragment order (zero-padded).

typedef __attribute__((ext_vector_type(8))) short short8;
typedef __attribute__((ext_vector_type(4))) float f32x4;

__device__ __forceinline__ unsigned short f2bf(float f) {
    unsigned int b = __float_as_uint(f);
    b = (b + 0x7fffu + ((b >> 16) & 1u)) >> 16;
    return (unsigned short)b;
}
__device__ __forceinline__ float bf2f(unsigned int u) {
    return __uint_as_float(u << 16);
}
__device__ __forceinline__ unsigned int pack2(float a, float b) {
    return (unsigned int)f2bf(a) | ((unsigned int)f2bf(b) << 16);
}

// ---------------- weight packing ----------------
// wp[((tap*nch + chunk)*Cout_pad + co)*32 + kin], kin = kb*8+j (ci = chunk*32+kin)
__global__ __launch_bounds__(256) void pack_w(
    const float* __restrict__ w, unsigned short* __restrict__ wp,
    int Cin_real, int Cout_real, int Cout_pad, int nch, int remap, int total)
{
    int idx = blockIdx.x * 256 + threadIdx.x;
    if (idx >= total) return;
    int kin = idx & 31;
    int t = idx >> 5;
    int co = t % Cout_pad; t /= Cout_pad;
    int chunk = t % nch;
    int tap = t / nch;
    int ci = chunk * 32 + kin;
    int cs = -1;
    if (remap) {               // conv5: concat ch -> wc_w1 ci (skip pad ch15)
        if (ci < 15) cs = ci;
        else if (ci >= 16 && ci <= 224) cs = ci - 1;
    } else {
        if (ci < Cin_real) cs = ci;
    }
    float val = 0.f;
    if (co < Cout_real && cs >= 0)
        val = w[(co * Cin_real + cs) * 9 + tap];
    wp[idx] = f2bf(val);
}

// ---------------- data -> concat NHWC bf16 ----------------
__global__ __launch_bounds__(256) void convert_data(
    const float* __restrict__ data, unsigned short* __restrict__ concat)
{
    int i = blockIdx.x * 256 + threadIdx.x;   // B*H*W
    int b = i >> 16, p = i & 65535;
    int base = i * 232;
#pragma unroll
    for (int c = 0; c < 15; ++c)
        concat[base + c] = f2bf(data[(b * 15 + c) * 65536 + p]);
    concat[base + 15] = 0;
}

// ---------------- MFMA conv ----------------
// block: 64 cout x 128 px (32x4), 4 waves (2m x 2n), K-chunks of 32 ch, 9 taps.
// mode 0: bf16 NHWC store; mode 1: f32 NCHW store (dstCs = Cout planes).
__global__ __launch_bounds__(256) void conv_mfma(
    const unsigned short* __restrict__ src, int srcCs, int srcOff,
    const unsigned short* __restrict__ wp, const float* __restrict__ bias,
    int nch, int Cout, int Cout_pad,
    void* __restrict__ dst, int dstCs, int dstOff, int mode, int relu)
{
    __shared__ uint4 ldsb[816];              // [kb(4)][halo px(204=34x6)] 16B each
    const int tid = threadIdx.x;
    const int lane = tid & 63;
    const int wv = tid >> 6;
    const int wm = wv & 1, wn = wv >> 1;
    const int bx = blockIdx.x, b = blockIdx.y, bz = blockIdx.z;
    const int x0 = (bx & 7) * 32, y0 = (bx >> 3) * 4;
    const int l15 = lane & 15, l4 = lane >> 4;

    f32x4 acc[2][4];
#pragma unroll
    for (int mt = 0; mt < 2; ++mt)
#pragma unroll
        for (int nt = 0; nt < 4; ++nt) acc[mt][nt] = (f32x4)0.f;

    for (int chunk = 0; chunk < nch; ++chunk) {
        __syncthreads();
        for (int s = tid; s < 816; s += 256) {
            int kb = s / 204, hp = s - kb * 204;
            int hy = hp / 34, hx = hp - hy * 34;
            int y = y0 - 1 + hy, x = x0 - 1 + hx;
            int ch = srcOff + chunk * 32 + kb * 8;
            uint4 v = make_uint4(0u, 0u, 0u, 0u);
            if ((unsigned)y < 256u && (unsigned)x < 256u && ch + 8 <= srcCs)
                v = *(const uint4*)(src + ((b * 65536 + y * 256 + x) * srcCs + ch));
            ldsb[s] = v;
        }
        __syncthreads();
#pragma unroll
        for (int tap = 0; tap < 9; ++tap) {
            const int dy = tap / 3, dx = tap - dy * 3;
            short8 af[2];
#pragma unroll
            for (int mt = 0; mt < 2; ++mt) {
                int co = bz * 64 + wm * 32 + mt * 16 + l15;
                af[mt] = *(const short8*)(wp +
                    (((tap * nch + chunk) * Cout_pad + co) * 4 + l4) * 8);
            }
#pragma unroll
            for (int nt = 0; nt < 4; ++nt) {
                int p = wn * 64 + nt * 16;
                int hp = ((p >> 5) + dy) * 34 + (p & 31) + l15 + dx;
                short8 bf = __builtin_bit_cast(short8, ldsb[l4 * 204 + hp]);
#pragma unroll
                for (int mt = 0; mt < 2; ++mt)
                    acc[mt][nt] = __builtin_amdgcn_mfma_f32_16x16x32_bf16(
                        af[mt], bf, acc[mt][nt], 0, 0, 0);
            }
        }
    }

    // epilogue: C/D frag: col(pixel)=lane&15, row(cout)=(lane>>4)*4+e
#pragma unroll
    for (int mt = 0; mt < 2; ++mt) {
        int co0 = bz * 64 + wm * 32 + mt * 16 + l4 * 4;
#pragma unroll
        for (int nt = 0; nt < 4; ++nt) {
            int p = wn * 64 + nt * 16 + l15;
            int y = y0 + (p >> 5), x = x0 + (p & 31);
            float v[4];
#pragma unroll
            for (int e = 0; e < 4; ++e) {
                int co = co0 + e;
                float f = acc[mt][nt][e] + ((co < Cout) ? bias[co] : 0.f);
                if (relu) f = fmaxf(f, 0.f);
                v[e] = f;
            }
            if (mode == 0) {
                unsigned short* d = (unsigned short*)dst +
                    ((b * 65536 + y * 256 + x) * dstCs + dstOff + co0);
                if (co0 + 3 < Cout) {
                    uint2 pk = make_uint2(pack2(v[0], v[1]), pack2(v[2], v[3]));
                    *(uint2*)d = pk;
                } else {
#pragma unroll
                    for (int e = 0; e < 4; ++e)
                        if (co0 + e < Cout) d[e] = f2bf(v[e]);
                }
            } else {
                float* d = (float*)dst + (b * dstCs + co0) * 65536 + y * 256 + x;
#pragma unroll
                for (int e = 0; e < 4; ++e)
                    if (co0 + e < Cout) d[e * 65536] = v[e];
            }
        }
    }
}

// ---------------- trilinear: offsets -> samples, in place in concat ----------------
__global__ __launch_bounds__(256) void trilin_kern(
    const float* __restrict__ data, unsigned short* __restrict__ concat,
    float* __restrict__ smp)
{
    int i = blockIdx.x * 256 + threadIdx.x;   // b*65536 + p
    int b = i >> 16, p = i & 65535;
    int y = p >> 8, x = p & 255;
    unsigned short* cptr = concat + i * 232 + 144;

    unsigned int wbuf[41];
    {
        const uint4* gp = (const uint4*)cptr;
#pragma unroll
        for (int k = 0; k < 10; ++k) {
            uint4 t = gp[k];
            wbuf[4 * k] = t.x; wbuf[4 * k + 1] = t.y;
            wbuf[4 * k + 2] = t.z; wbuf[4 * k + 3] = t.w;
        }
        wbuf[40] = (unsigned int)cptr[80];
    }

#pragma unroll
    for (int s = 0; s < 27; ++s) {
        int L0 = 3 * s;
        float o0 = bf2f((wbuf[L0 >> 1] >> ((L0 & 1) * 16)) & 0xffffu);
        float o1 = bf2f((wbuf[(L0 + 1) >> 1] >> (((L0 + 1) & 1) * 16)) & 0xffffu);
        float o2 = bf2f((wbuf[(L0 + 2) >> 1] >> (((L0 + 2) & 1) * 16)) & 0xffffu);

        float kd = (float)(s / 9 - 1);
        float kh = (float)((s / 3) % 3 - 1);
        float kw = (float)(s % 3 - 1);
        float pd = 2.0f + kd + o0;
        float ph = (float)y + kh + o1;
        float pw = (float)x + kw + o2;
        pd = fminf(fmaxf(pd, 0.f), 4.f);
        ph = fminf(fmaxf(ph, 0.f), 255.f);
        pw = fminf(fmaxf(pw, 0.f), 255.f);
        float d0 = floorf(pd), h0 = floorf(ph), w0 = floorf(pw);
        float fd = pd - d0, fh = ph - h0, fw = pw - w0;
        int d0i = (int)d0, h0i = (int)h0, w0i = (int)w0;
        int d1i = min(d0i + 1, 4), h1i = min(h0i + 1, 255), w1i = min(w0i + 1, 255);

        float res[3];
#pragma unroll
        for (int c = 0; c < 3; ++c) {
            const float* dp = data + ((b * 5 + d0i) * 3 + c) * 65536;
            const float* dp1 = data + ((b * 5 + d1i) * 3 + c) * 65536;
            int a00 = (h0i << 8) + w0i, a01 = (h0i << 8) + w1i;
            int a10 = (h1i << 8) + w0i, a11 = (h1i << 8) + w1i;
            float r0 = (dp[a00] * (1.f - fw) + dp[a01] * fw) * (1.f - fh)
                     + (dp[a10] * (1.f - fw) + dp[a11] * fw) * fh;
            float r1 = (dp1[a00] * (1.f - fw) + dp1[a01] * fw) * (1.f - fh)
                     + (dp1[a10] * (1.f - fw) + dp1[a11] * fw) * fh;
            float r = r0 * (1.f - fd) + r1 * fd;
            res[c] = r;
            smp[((b * 27 + s) * 3 + c) * 65536 + p] = r;
        }
        // pack samples back over the offsets (same register words)
#pragma unroll
        for (int c = 0; c < 3; ++c) {
            int L = L0 + c;
            unsigned int u = (unsigned int)f2bf(res[c]);
            if (L & 1) wbuf[L >> 1] = (wbuf[L >> 1] & 0xffffu) | (u << 16);
            else       wbuf[L >> 1] = (wbuf[L >> 1] & 0xffff0000u) | u;
        }
    }

    wbuf[40] &= 0xffffu;
    uint4* gp = (uint4*)cptr;
#pragma unroll
    for (int k = 0; k < 10; ++k)
        gp[k] = make_uint4(wbuf[4 * k], wbuf[4 * k + 1], wbuf[4 * k + 2], wbuf[4 * k + 3]);
    *(unsigned int*)(cptr + 80) = wbuf[40];
}

// ---------------- combine ----------------
__global__ __launch_bounds__(256) void combine_kern(
    const float* __restrict__ smp, const float* __restrict__ wt,
    float* __restrict__ res_i, float* __restrict__ outp)
{
    int i = blockIdx.x * 256 + threadIdx.x;   // B*H*W
    int p = i & 65535;
    int b = i >> 16;
    float ov[3] = {0.f, 0.f, 0.f};
#pragma unroll
    for (int g = 0; g < 3; ++g) {
        float r[3] = {0.f, 0.f, 0.f};
#pragma unroll
        for (int k = 0; k < 9; ++k) {
            int s = g * 9 + k;
            float w = wt[((b * 27 + s) << 16) + p];
#pragma unroll
            for (int c = 0; c < 3; ++c)
                r[c] = fmaf(smp[(((b * 27 + s) * 3 + c) << 16) + p], w, r[c]);
        }
#pragma unroll
        for (int c = 0; c < 3; ++c) {
            res_i[(((b * 3 + g) * 3 + c) << 16) + p] = 3.f * r[c];
            ov[c] += r[c];
        }
    }
#pragma unroll
    for (int c = 0; c < 3; ++c)
        outp[((b * 3 + c) << 16) + p] = ov[c];
}

extern "C" void kernel_launch(void* const* d_in, const int* in_sizes, int n_in,
                              void* d_out, int out_size, void* d_ws, size_t ws_size,
                              hipStream_t stream)
{
    const float* data   = (const float*)d_in[0];
    const float* enc_w1 = (const float*)d_in[1];
    const float* enc_b1 = (const float*)d_in[2];
    const float* enc_w2 = (const float*)d_in[3];
    const float* enc_b2 = (const float*)d_in[4];
    const float* off_w  = (const float*)d_in[5];
    const float* off_b  = (const float*)d_in[6];
    const float* wc_w1  = (const float*)d_in[7];
    const float* wc_b1  = (const float*)d_in[8];
    const float* wc_w2  = (const float*)d_in[9];
    const float* wc_b2  = (const float*)d_in[10];
    const float* wc_w3  = (const float*)d_in[11];
    const float* wc_b3  = (const float*)d_in[12];

    float* dout  = (float*)d_out;
    float* res_i = dout;                  // [4,3,3,256,256]
    float* outp  = dout + 2359296;        // [4,3,256,256]
    float* smp   = dout + 3145728;        // [4,27,3,256,256] fp32 NCHW

    char* ws = (char*)d_ws;
    unsigned short* concat = (unsigned short*)ws;                      // 121,634,816 B
    unsigned short* buf_a  = (unsigned short*)(ws + 121634816);        // 33,554,432 B
    unsigned short* buf_b  = (unsigned short*)(ws + 155189248);        // 33,554,432 B
    unsigned short* wpk    = (unsigned short*)(ws + 188743680);        // 921,600 B
    unsigned short* wp1 = wpk;            // 9*1*64*32  = 18432
    unsigned short* wp2 = wpk + 18432;    // 9*2*128*32 = 73728
    unsigned short* wp3 = wpk + 92160;    // 9*4*128*32 = 147456
    unsigned short* wp5 = wpk + 239616;   // 9*8*64*32  = 147456
    unsigned short* wp6 = wpk + 387072;   // 9*2*64*32  = 36864
    unsigned short* wp7 = wpk + 423936;   // 9*2*64*32  = 36864
    float* wconv = (float*)buf_a;         // conv7 out, f32 NCHW [4][27][HW]

    dim3 blk(256);

    pack_w<<<72, blk, 0, stream>>>(enc_w1, wp1, 15, 64, 64, 1, 0, 18432);
    pack_w<<<288, blk, 0, stream>>>(enc_w2, wp2, 64, 128, 128, 2, 0, 73728);
    pack_w<<<576, blk, 0, stream>>>(off_w, wp3, 128, 81, 128, 4, 0, 147456);
    pack_w<<<576, blk, 0, stream>>>(wc_w1, wp5, 224, 64, 64, 8, 1, 147456);
    pack_w<<<144, blk, 0, stream>>>(wc_w2, wp6, 64, 64, 64, 2, 0, 36864);
    pack_w<<<144, blk, 0, stream>>>(wc_w3, wp7, 64, 27, 64, 2, 0, 36864);
    convert_data<<<1024, blk, 0, stream>>>(data, concat);

    // conv1: concat ch0-31 (zero-wt >=15) -> f1 (buf_a, NHWC 64)
    conv_mfma<<<dim3(512, 4, 1), blk, 0, stream>>>(
        concat, 232, 0, wp1, enc_b1, 1, 64, 64, buf_a, 64, 0, 0, 1);
    // conv2: f1 -> feature (concat ch16-143)
    conv_mfma<<<dim3(512, 4, 2), blk, 0, stream>>>(
        buf_a, 64, 0, wp2, enc_b2, 2, 128, 128, concat, 232, 16, 0, 1);
    // conv3: feature -> offsets (concat ch144-224)
    conv_mfma<<<dim3(512, 4, 2), blk, 0, stream>>>(
        concat, 232, 16, wp3, off_b, 4, 81, 128, concat, 232, 144, 0, 0);
    // trilinear: offsets -> samples (in place) + fp32 NCHW to d_out
    trilin_kern<<<1024, blk, 0, stream>>>(data, concat, smp);
    // conv5: concat 232(->256 pad) -> h1 (buf_a)
    conv_mfma<<<dim3(512, 4, 1), blk, 0, stream>>>(
        concat, 232, 0, wp5, wc_b1, 8, 64, 64, buf_a, 64, 0, 0, 1);
    // conv6: h1 -> h2 (buf_b)
    conv_mfma<<<dim3(512, 4, 1), blk, 0, stream>>>(
        buf_a, 64, 0, wp6, wc_b2, 2, 64, 64, buf_b, 64, 0, 0, 1);
    // conv7: h2 -> weights (f32 NCHW, buf_a)
    conv_mfma<<<dim3(512, 4, 1), blk, 0, stream>>>(
        buf_b, 64, 0, wp7, wc_b3, 2, 27, 64, wconv, 27, 0, 1, 0);
    // combine
    combine_kern<<<1024, blk, 0, stream>>>(smp, wconv, res_i, outp);
}

// Round 5
// 814.524 us; speedup vs baseline: 9.3061x; 1.0062x over previous
//
#include <hip/hip_runtime.h>

// Deformable KPN, bf16 MFMA implicit-GEMM pipeline, round 5 (= round 4 resubmit
// with hardened wave-uniform global_load_lds destination).
// B=4, D=5, C=3, H=W=256, S=27, GROUPS=3.

typedef __attribute__((ext_vector_type(8))) short short8;
typedef __attribute__((ext_vector_type(4))) float f32x4;

__device__ __forceinline__ unsigned short f2bf(float f) {
    unsigned int b = __float_as_uint(f);
    b = (b + 0x7fffu + ((b >> 16) & 1u)) >> 16;
    return (unsigned short)b;
}
__device__ __forceinline__ float bf2f(unsigned int u) {
    return __uint_as_float(u << 16);
}
__device__ __forceinline__ unsigned int pack2(float a, float b) {
    return (unsigned int)f2bf(a) | ((unsigned int)f2bf(b) << 16);
}

// ---------------- fused weight packing + zero-page ----------------
// wp[((tap*nch + chunk)*Cout_pad + co)*32 + kin], kin = kb*8+j (ci = chunk*32+kin)
__global__ __launch_bounds__(256) void prep_kern(
    const float* __restrict__ w1, const float* __restrict__ w2,
    const float* __restrict__ w3, const float* __restrict__ w5,
    const float* __restrict__ w6, const float* __restrict__ w7,
    unsigned short* __restrict__ wpk)
{
    int idx = blockIdx.x * 256 + threadIdx.x;
    if (idx < 460800) {
        const float* w; int off, CinR, CoutR, CoutP, nch, remap;
        if (idx < 18432)       { w = w1; off = 0;      CinR = 15;  CoutR = 64;  CoutP = 64;  nch = 1; remap = 0; }
        else if (idx < 92160)  { w = w2; off = 18432;  CinR = 64;  CoutR = 128; CoutP = 128; nch = 2; remap = 0; }
        else if (idx < 239616) { w = w3; off = 92160;  CinR = 128; CoutR = 81;  CoutP = 128; nch = 4; remap = 0; }
        else if (idx < 387072) { w = w5; off = 239616; CinR = 224; CoutR = 64;  CoutP = 64;  nch = 8; remap = 1; }
        else if (idx < 423936) { w = w6; off = 387072; CinR = 64;  CoutR = 64;  CoutP = 64;  nch = 2; remap = 0; }
        else                   { w = w7; off = 423936; CinR = 64;  CoutR = 27;  CoutP = 64;  nch = 2; remap = 0; }
        int li = idx - off;
        int kin = li & 31;
        int t = li >> 5;
        int co = t % CoutP; t /= CoutP;
        int chunk = t % nch;
        int tap = t / nch;
        int ci = chunk * 32 + kin;
        int cs = -1;
        if (remap) {            // concat ch -> wc_w1 ci (skip pad ch15)
            if (ci < 15) cs = ci;
            else if (ci >= 16 && ci <= 224) cs = ci - 1;
        } else {
            if (ci < CinR) cs = ci;
        }
        float val = 0.f;
        if (co < CoutR && cs >= 0)
            val = w[(co * CinR + cs) * 9 + tap];
        wpk[idx] = f2bf(val);
    } else if (idx < 460800 + 8192) {
        wpk[idx] = 0;           // zero page (16 KB) right after packed weights
    }
}

// ---------------- data -> concat NHWC bf16 ----------------
__global__ __launch_bounds__(256) void convert_data(
    const float* __restrict__ data, unsigned short* __restrict__ concat)
{
    int i = blockIdx.x * 256 + threadIdx.x;   // B*H*W
    int b = i >> 16, p = i & 65535;
    int base = i * 232;
#pragma unroll
    for (int c = 0; c < 15; ++c)
        concat[base + c] = f2bf(data[(b * 15 + c) * 65536 + p]);
    concat[base + 15] = 0;
}

// ---------------- MFMA conv ----------------
// block 256 thr (4 waves). Output tile: 64co x 256px (4 rows y0..y0+3, 64 cols).
// Wave wv owns row y0+wv; mt<=4 co-tiles of 16; nt=4 px-tiles of 16.
// Staging: wave wv stages kb=wv (8 ch) of the 66x6 halo via global_load_lds
// (wave-uniform LDS base, HW adds lane*16), double-buffered, one barrier/chunk.
__global__ __launch_bounds__(256) void conv_mfma(
    const unsigned short* __restrict__ src, int srcCs, int srcOff,
    const unsigned short* __restrict__ wp, const float* __restrict__ bias,
    int nch, int Cout, int Cout_pad,
    void* __restrict__ dst, int dstCs, int dstOff, int mode, int relu,
    const uint4* __restrict__ zp)
{
    __shared__ uint4 ldsb[2][1584];          // 2 x 4kb x 396(=66x6) x 16B = 50688 B
    const int tid = threadIdx.x;
    const int lane = tid & 63;
    const int wv = tid >> 6;
    const int bx = blockIdx.x, b = blockIdx.y, bz = blockIdx.z;
    const int x0 = (bx & 3) * 64, y0 = (bx >> 2) * 4;
    const int l15 = lane & 15, l4 = lane >> 4;
    const int mtc = min(4, (Cout - bz * 64 + 15) >> 4);

    f32x4 acc[4][4];
#pragma unroll
    for (int m = 0; m < 4; ++m)
#pragma unroll
        for (int nt = 0; nt < 4; ++nt) acc[m][nt] = (f32x4)0.f;

    // ---- staging: wave wv handles kb=wv ----
    auto stage = [&](int buf, int chunk) {
        int ch = srcOff + chunk * 32 + wv * 8;
        bool chok = (ch + 8 <= srcCs);
        const unsigned short* sbase = src + ch;
#pragma unroll
        for (int it = 0; it < 7; ++it) {
            int r = it * 64 + lane;
            if (r < 396) {
                int hy = r / 66, hx = r - hy * 66;
                int y = y0 - 1 + hy, x = x0 - 1 + hx;
                const uint4* g;
                if (chok && (unsigned)y < 256u && (unsigned)x < 256u)
                    g = (const uint4*)(sbase + (b * 65536 + y * 256 + x) * srcCs);
                else
                    g = zp + lane;
                // LDS dest: wave-uniform base; HW writes base + lane*16
                __builtin_amdgcn_global_load_lds(
                    (const __attribute__((address_space(1))) void*)g,
                    (__attribute__((address_space(3))) void*)&ldsb[buf][wv * 396 + it * 64],
                    16, 0, 0);
            }
        }
    };

    stage(0, 0);
    int buf = 0;
    for (int c = 0; c < nch; ++c) {
        __syncthreads();                    // drains vmcnt (staged data ready)
        if (c + 1 < nch) stage(buf ^ 1, c + 1);
#pragma unroll
        for (int tap = 0; tap < 9; ++tap) {
            const int dy = tap / 3, dx = tap - dy * 3;
            short8 af[4];
#pragma unroll
            for (int m = 0; m < 4; ++m)
                if (m < mtc)
                    af[m] = *(const short8*)(wp +
                        ((tap * nch + c) * Cout_pad + bz * 64 + m * 16 + l15) * 32 + l4 * 8);
#pragma unroll
            for (int nt = 0; nt < 4; ++nt) {
                int hx = nt * 16 + l15 + dx;         // halo x (origin -1)
                int hy = wv + dy;                     // halo y
                short8 bf = __builtin_bit_cast(short8,
                    ldsb[buf][l4 * 396 + hy * 66 + hx]);
#pragma unroll
                for (int m = 0; m < 4; ++m)
                    if (m < mtc)
                        acc[m][nt] = __builtin_amdgcn_mfma_f32_16x16x32_bf16(
                            af[m], bf, acc[m][nt], 0, 0, 0);
            }
        }
        buf ^= 1;
    }

    // epilogue: C/D frag: col(px)=lane&15, row(co)=(lane>>4)*4+e
    const int y = y0 + wv;
#pragma unroll
    for (int m = 0; m < 4; ++m) {
        if (m >= mtc) continue;
        int co0 = bz * 64 + m * 16 + l4 * 4;
#pragma unroll
        for (int nt = 0; nt < 4; ++nt) {
            int x = x0 + nt * 16 + l15;
            float v[4];
#pragma unroll
            for (int e = 0; e < 4; ++e) {
                int co = co0 + e;
                float f = acc[m][nt][e] + ((co < Cout) ? bias[co] : 0.f);
                if (relu) f = fmaxf(f, 0.f);
                v[e] = f;
            }
            if (mode == 0) {
                unsigned short* d = (unsigned short*)dst +
                    ((b * 65536 + y * 256 + x) * dstCs + dstOff + co0);
                if (co0 + 3 < Cout) {
                    uint2 pk = make_uint2(pack2(v[0], v[1]), pack2(v[2], v[3]));
                    *(uint2*)d = pk;
                } else {
#pragma unroll
                    for (int e = 0; e < 4; ++e)
                        if (co0 + e < Cout) d[e] = f2bf(v[e]);
                }
            } else {
                float* d = (float*)dst + (b * dstCs + co0) * 65536 + y * 256 + x;
#pragma unroll
                for (int e = 0; e < 4; ++e)
                    if (co0 + e < Cout) d[e * 65536] = v[e];
            }
        }
    }
}

// ---------------- trilinear: offsets -> samples, in place in concat ----------------
__global__ __launch_bounds__(256) void trilin_kern(
    const float* __restrict__ data, unsigned short* __restrict__ concat,
    float* __restrict__ smp)
{
    int i = blockIdx.x * 256 + threadIdx.x;   // b*65536 + p
    int b = i >> 16, p = i & 65535;
    int y = p >> 8, x = p & 255;
    unsigned short* cptr = concat + i * 232 + 144;

    unsigned int wbuf[41];
    {
        const uint4* gp = (const uint4*)cptr;
#pragma unroll
        for (int k = 0; k < 10; ++k) {
            uint4 t = gp[k];
            wbuf[4 * k] = t.x; wbuf[4 * k + 1] = t.y;
            wbuf[4 * k + 2] = t.z; wbuf[4 * k + 3] = t.w;
        }
        wbuf[40] = (unsigned int)cptr[80];
    }

#pragma unroll
    for (int s = 0; s < 27; ++s) {
        int L0 = 3 * s;
        float o0 = bf2f((wbuf[L0 >> 1] >> ((L0 & 1) * 16)) & 0xffffu);
        float o1 = bf2f((wbuf[(L0 + 1) >> 1] >> (((L0 + 1) & 1) * 16)) & 0xffffu);
        float o2 = bf2f((wbuf[(L0 + 2) >> 1] >> (((L0 + 2) & 1) * 16)) & 0xffffu);

        float kd = (float)(s / 9 - 1);
        float kh = (float)((s / 3) % 3 - 1);
        float kw = (float)(s % 3 - 1);
        float pd = 2.0f + kd + o0;
        float ph = (float)y + kh + o1;
        float pw = (float)x + kw + o2;
        pd = fminf(fmaxf(pd, 0.f), 4.f);
        ph = fminf(fmaxf(ph, 0.f), 255.f);
        pw = fminf(fmaxf(pw, 0.f), 255.f);
        float d0 = floorf(pd), h0 = floorf(ph), w0 = floorf(pw);
        float fd = pd - d0, fh = ph - h0, fw = pw - w0;
        int d0i = (int)d0, h0i = (int)h0, w0i = (int)w0;
        int d1i = min(d0i + 1, 4), h1i = min(h0i + 1, 255), w1i = min(w0i + 1, 255);

        float res[3];
#pragma unroll
        for (int c = 0; c < 3; ++c) {
            const float* dp = data + ((b * 5 + d0i) * 3 + c) * 65536;
            const float* dp1 = data + ((b * 5 + d1i) * 3 + c) * 65536;
            int a00 = (h0i << 8) + w0i, a01 = (h0i << 8) + w1i;
            int a10 = (h1i << 8) + w0i, a11 = (h1i << 8) + w1i;
            float r0 = (dp[a00] * (1.f - fw) + dp[a01] * fw) * (1.f - fh)
                     + (dp[a10] * (1.f - fw) + dp[a11] * fw) * fh;
            float r1 = (dp1[a00] * (1.f - fw) + dp1[a01] * fw) * (1.f - fh)
                     + (dp1[a10] * (1.f - fw) + dp1[a11] * fw) * fh;
            float r = r0 * (1.f - fd) + r1 * fd;
            res[c] = r;
            smp[((b * 27 + s) * 3 + c) * 65536 + p] = r;
        }
#pragma unroll
        for (int c = 0; c < 3; ++c) {
            int L = L0 + c;
            unsigned int u = (unsigned int)f2bf(res[c]);
            if (L & 1) wbuf[L >> 1] = (wbuf[L >> 1] & 0xffffu) | (u << 16);
            else       wbuf[L >> 1] = (wbuf[L >> 1] & 0xffff0000u) | u;
        }
    }

    wbuf[40] &= 0xffffu;
    uint4* gp = (uint4*)cptr;
#pragma unroll
    for (int k = 0; k < 10; ++k)
        gp[k] = make_uint4(wbuf[4 * k], wbuf[4 * k + 1], wbuf[4 * k + 2], wbuf[4 * k + 3]);
    *(unsigned int*)(cptr + 80) = wbuf[40];
}

// ---------------- combine ----------------
__global__ __launch_bounds__(256) void combine_kern(
    const float* __restrict__ smp, const float* __restrict__ wt,
    float* __restrict__ res_i, float* __restrict__ outp)
{
    int i = blockIdx.x * 256 + threadIdx.x;   // B*H*W
    int p = i & 65535;
    int b = i >> 16;
    float ov[3] = {0.f, 0.f, 0.f};
#pragma unroll
    for (int g = 0; g < 3; ++g) {
        float r[3] = {0.f, 0.f, 0.f};
#pragma unroll
        for (int k = 0; k < 9; ++k) {
            int s = g * 9 + k;
            float w = wt[((b * 27 + s) << 16) + p];
#pragma unroll
            for (int c = 0; c < 3; ++c)
                r[c] = fmaf(smp[(((b * 27 + s) * 3 + c) << 16) + p], w, r[c]);
        }
#pragma unroll
        for (int c = 0; c < 3; ++c) {
            res_i[(((b * 3 + g) * 3 + c) << 16) + p] = 3.f * r[c];
            ov[c] += r[c];
        }
    }
#pragma unroll
    for (int c = 0; c < 3; ++c)
        outp[((b * 3 + c) << 16) + p] = ov[c];
}

extern "C" void kernel_launch(void* const* d_in, const int* in_sizes, int n_in,
                              void* d_out, int out_size, void* d_ws, size_t ws_size,
                              hipStream_t stream)
{
    const float* data   = (const float*)d_in[0];
    const float* enc_w1 = (const float*)d_in[1];
    const float* enc_b1 = (const float*)d_in[2];
    const float* enc_w2 = (const float*)d_in[3];
    const float* enc_b2 = (const float*)d_in[4];
    const float* off_w  = (const float*)d_in[5];
    const float* off_b  = (const float*)d_in[6];
    const float* wc_w1  = (const float*)d_in[7];
    const float* wc_b1  = (const float*)d_in[8];
    const float* wc_w2  = (const float*)d_in[9];
    const float* wc_b2  = (const float*)d_in[10];
    const float* wc_w3  = (const float*)d_in[11];
    const float* wc_b3  = (const float*)d_in[12];

    float* dout  = (float*)d_out;
    float* res_i = dout;                  // [4,3,3,256,256]
    float* outp  = dout + 2359296;        // [4,3,256,256]
    float* smp   = dout + 3145728;        // [4,27,3,256,256] fp32 NCHW

    char* ws = (char*)d_ws;
    unsigned short* concat = (unsigned short*)ws;                      // 121,634,816 B
    unsigned short* buf_a  = (unsigned short*)(ws + 121634816);        // 33,554,432 B
    unsigned short* buf_b  = (unsigned short*)(ws + 155189248);        // 33,554,432 B
    unsigned short* wpk    = (unsigned short*)(ws + 188743680);        // 921,600 B + 16 KB zp
    unsigned short* wp1 = wpk;            // 9*1*64*32  = 18432
    unsigned short* wp2 = wpk + 18432;    // 9*2*128*32 = 73728
    unsigned short* wp3 = wpk + 92160;    // 9*4*128*32 = 147456
    unsigned short* wp5 = wpk + 239616;   // 9*8*64*32  = 147456
    unsigned short* wp6 = wpk + 387072;   // 9*2*64*32  = 36864
    unsigned short* wp7 = wpk + 423936;   // 9*2*64*32  = 36864
    const uint4* zp = (const uint4*)(wpk + 460800);   // 16 KB zeros
    float* wconv = (float*)buf_a;         // conv7 out, f32 NCHW [4][27][HW]

    dim3 blk(256);

    prep_kern<<<1832, blk, 0, stream>>>(enc_w1, enc_w2, off_w, wc_w1, wc_w2, wc_w3, wpk);
    convert_data<<<1024, blk, 0, stream>>>(data, concat);

    // conv1: concat ch0-31 (zero-wt >=15) -> f1 (buf_a, NHWC 64)
    conv_mfma<<<dim3(256, 4, 1), blk, 0, stream>>>(
        concat, 232, 0, wp1, enc_b1, 1, 64, 64, buf_a, 64, 0, 0, 1, zp);
    // conv2: f1 -> feature (concat ch16-143)
    conv_mfma<<<dim3(256, 4, 2), blk, 0, stream>>>(
        buf_a, 64, 0, wp2, enc_b2, 2, 128, 128, concat, 232, 16, 0, 1, zp);
    // conv3: feature -> offsets (concat ch144-224); bz1 computes only 2 co-tiles
    conv_mfma<<<dim3(256, 4, 2), blk, 0, stream>>>(
        concat, 232, 16, wp3, off_b, 4, 81, 128, concat, 232, 144, 0, 0, zp);
    // trilinear: offsets -> samples (in place) + fp32 NCHW to d_out
    trilin_kern<<<1024, blk, 0, stream>>>(data, concat, smp);
    // conv5: concat 232(->256 pad) -> h1 (buf_a)
    conv_mfma<<<dim3(256, 4, 1), blk, 0, stream>>>(
        concat, 232, 0, wp5, wc_b1, 8, 64, 64, buf_a, 64, 0, 0, 1, zp);
    // conv6: h1 -> h2 (buf_b)
    conv_mfma<<<dim3(256, 4, 1), blk, 0, stream>>>(
        buf_a, 64, 0, wp6, wc_b2, 2, 64, 64, buf_b, 64, 0, 0, 1, zp);
    // conv7: h2 -> weights (f32 NCHW, buf_a); mtc=2 (27->32)
    conv_mfma<<<dim3(256, 4, 1), blk, 0, stream>>>(
        buf_b, 64, 0, wp7, wc_b3, 2, 27, 64, wconv, 27, 0, 1, 0, zp);
    // combine
    combine_kern<<<1024, blk, 0, stream>>>(smp, wconv, res_i, outp);
}

// Round 6
// 744.192 us; speedup vs baseline: 10.1856x; 1.0945x over previous
//
#include <hip/hip_runtime.h>

// Deformable KPN, bf16 MFMA implicit-GEMM pipeline, round 6.
// B=4, D=5, C=3, H=W=256, S=27, GROUPS=3.
// vs round 5:
//  - trilinear samples from channel-packed [B][D][HW][4] bf16 texture (8B/corner)
//  - combine fused into conv7 epilogue (LDS weight transpose); combine_kern gone
//  - packed texture lives in buf_b (free until conv6)

typedef __attribute__((ext_vector_type(8))) short short8;
typedef __attribute__((ext_vector_type(4))) float f32x4;

__device__ __forceinline__ unsigned short f2bf(float f) {
    unsigned int b = __float_as_uint(f);
    b = (b + 0x7fffu + ((b >> 16) & 1u)) >> 16;
    return (unsigned short)b;
}
__device__ __forceinline__ float bf2f(unsigned int u) {
    return __uint_as_float(u << 16);
}
__device__ __forceinline__ unsigned int pack2(float a, float b) {
    return (unsigned int)f2bf(a) | ((unsigned int)f2bf(b) << 16);
}

// ---------------- fused weight packing + zero-page ----------------
// wp[((tap*nch + chunk)*Cout_pad + co)*32 + kin], kin = kb*8+j (ci = chunk*32+kin)
__global__ __launch_bounds__(256) void prep_kern(
    const float* __restrict__ w1, const float* __restrict__ w2,
    const float* __restrict__ w3, const float* __restrict__ w5,
    const float* __restrict__ w6, const float* __restrict__ w7,
    unsigned short* __restrict__ wpk)
{
    int idx = blockIdx.x * 256 + threadIdx.x;
    if (idx < 460800) {
        const float* w; int off, CinR, CoutR, CoutP, nch, remap;
        if (idx < 18432)       { w = w1; off = 0;      CinR = 15;  CoutR = 64;  CoutP = 64;  nch = 1; remap = 0; }
        else if (idx < 92160)  { w = w2; off = 18432;  CinR = 64;  CoutR = 128; CoutP = 128; nch = 2; remap = 0; }
        else if (idx < 239616) { w = w3; off = 92160;  CinR = 128; CoutR = 81;  CoutP = 128; nch = 4; remap = 0; }
        else if (idx < 387072) { w = w5; off = 239616; CinR = 224; CoutR = 64;  CoutP = 64;  nch = 8; remap = 1; }
        else if (idx < 423936) { w = w6; off = 387072; CinR = 64;  CoutR = 64;  CoutP = 64;  nch = 2; remap = 0; }
        else                   { w = w7; off = 423936; CinR = 64;  CoutR = 27;  CoutP = 64;  nch = 2; remap = 0; }
        int li = idx - off;
        int kin = li & 31;
        int t = li >> 5;
        int co = t % CoutP; t /= CoutP;
        int chunk = t % nch;
        int tap = t / nch;
        int ci = chunk * 32 + kin;
        int cs = -1;
        if (remap) {            // concat ch -> wc_w1 ci (skip pad ch15)
            if (ci < 15) cs = ci;
            else if (ci >= 16 && ci <= 224) cs = ci - 1;
        } else {
            if (ci < CinR) cs = ci;
        }
        float val = 0.f;
        if (co < CoutR && cs >= 0)
            val = w[(co * CinR + cs) * 9 + tap];
        wpk[idx] = f2bf(val);
    } else if (idx < 460800 + 8192) {
        wpk[idx] = 0;           // zero page (16 KB) right after packed weights
    }
}

// ---------------- data -> concat NHWC bf16 ----------------
__global__ __launch_bounds__(256) void convert_data(
    const float* __restrict__ data, unsigned short* __restrict__ concat)
{
    int i = blockIdx.x * 256 + threadIdx.x;   // B*H*W
    int b = i >> 16, p = i & 65535;
    int base = i * 232;
#pragma unroll
    for (int c = 0; c < 15; ++c)
        concat[base + c] = f2bf(data[(b * 15 + c) * 65536 + p]);
    concat[base + 15] = 0;
}

// ---------------- data -> packed sampling texture [B][D][HW][4] bf16 ----------------
__global__ __launch_bounds__(256) void pack_dpk(
    const float* __restrict__ data, unsigned short* __restrict__ dpk)
{
    int i = blockIdx.x * 256 + threadIdx.x;   // B*D*H*W = 1,310,720
    int bd = i >> 16, p = i & 65535;
    unsigned int w0 = pack2(data[(bd * 3 + 0) * 65536 + p],
                            data[(bd * 3 + 1) * 65536 + p]);
    unsigned int w1 = (unsigned int)f2bf(data[(bd * 3 + 2) * 65536 + p]);
    *(uint2*)(dpk + i * 4) = make_uint2(w0, w1);
}

// ---------------- MFMA conv ----------------
// block 256 thr (4 waves). Output tile: 64co x 256px (4 rows y0..y0+3, 64 cols).
// Wave wv owns row y0+wv; mt<=4 co-tiles of 16; nt=4 px-tiles of 16.
// Staging: wave wv stages kb=wv (8 ch) of the 66x6 halo via global_load_lds
// (wave-uniform LDS base, HW adds lane*16), double-buffered, one barrier/chunk.
__global__ __launch_bounds__(256) void conv_mfma(
    const unsigned short* __restrict__ src, int srcCs, int srcOff,
    const unsigned short* __restrict__ wp, const float* __restrict__ bias,
    int nch, int Cout, int Cout_pad,
    void* __restrict__ dst, int dstCs, int dstOff, int mode, int relu,
    const uint4* __restrict__ zp)
{
    __shared__ uint4 ldsb[2][1584];          // 2 x 4kb x 396(=66x6) x 16B = 50688 B
    const int tid = threadIdx.x;
    const int lane = tid & 63;
    const int wv = tid >> 6;
    const int bx = blockIdx.x, b = blockIdx.y, bz = blockIdx.z;
    const int x0 = (bx & 3) * 64, y0 = (bx >> 2) * 4;
    const int l15 = lane & 15, l4 = lane >> 4;
    const int mtc = min(4, (Cout - bz * 64 + 15) >> 4);

    f32x4 acc[4][4];
#pragma unroll
    for (int m = 0; m < 4; ++m)
#pragma unroll
        for (int nt = 0; nt < 4; ++nt) acc[m][nt] = (f32x4)0.f;

    auto stage = [&](int buf, int chunk) {
        int ch = srcOff + chunk * 32 + wv * 8;
        bool chok = (ch + 8 <= srcCs);
        const unsigned short* sbase = src + ch;
#pragma unroll
        for (int it = 0; it < 7; ++it) {
            int r = it * 64 + lane;
            if (r < 396) {
                int hy = r / 66, hx = r - hy * 66;
                int y = y0 - 1 + hy, x = x0 - 1 + hx;
                const uint4* g;
                if (chok && (unsigned)y < 256u && (unsigned)x < 256u)
                    g = (const uint4*)(sbase + (b * 65536 + y * 256 + x) * srcCs);
                else
                    g = zp + lane;
                __builtin_amdgcn_global_load_lds(
                    (const __attribute__((address_space(1))) void*)g,
                    (__attribute__((address_space(3))) void*)&ldsb[buf][wv * 396 + it * 64],
                    16, 0, 0);
            }
        }
    };

    stage(0, 0);
    int buf = 0;
    for (int c = 0; c < nch; ++c) {
        __syncthreads();
        if (c + 1 < nch) stage(buf ^ 1, c + 1);
#pragma unroll
        for (int tap = 0; tap < 9; ++tap) {
            const int dy = tap / 3, dx = tap - dy * 3;
            short8 af[4];
#pragma unroll
            for (int m = 0; m < 4; ++m)
                if (m < mtc)
                    af[m] = *(const short8*)(wp +
                        ((tap * nch + c) * Cout_pad + bz * 64 + m * 16 + l15) * 32 + l4 * 8);
#pragma unroll
            for (int nt = 0; nt < 4; ++nt) {
                int hx = nt * 16 + l15 + dx;
                int hy = wv + dy;
                short8 bf = __builtin_bit_cast(short8,
                    ldsb[buf][l4 * 396 + hy * 66 + hx]);
#pragma unroll
                for (int m = 0; m < 4; ++m)
                    if (m < mtc)
                        acc[m][nt] = __builtin_amdgcn_mfma_f32_16x16x32_bf16(
                            af[m], bf, acc[m][nt], 0, 0, 0);
            }
        }
        buf ^= 1;
    }

    const int y = y0 + wv;
#pragma unroll
    for (int m = 0; m < 4; ++m) {
        if (m >= mtc) continue;
        int co0 = bz * 64 + m * 16 + l4 * 4;
#pragma unroll
        for (int nt = 0; nt < 4; ++nt) {
            int x = x0 + nt * 16 + l15;
            float v[4];
#pragma unroll
            for (int e = 0; e < 4; ++e) {
                int co = co0 + e;
                float f = acc[m][nt][e] + ((co < Cout) ? bias[co] : 0.f);
                if (relu) f = fmaxf(f, 0.f);
                v[e] = f;
            }
            if (mode == 0) {
                unsigned short* d = (unsigned short*)dst +
                    ((b * 65536 + y * 256 + x) * dstCs + dstOff + co0);
                if (co0 + 3 < Cout) {
                    uint2 pk = make_uint2(pack2(v[0], v[1]), pack2(v[2], v[3]));
                    *(uint2*)d = pk;
                } else {
#pragma unroll
                    for (int e = 0; e < 4; ++e)
                        if (co0 + e < Cout) d[e] = f2bf(v[e]);
                }
            } else {
                float* d = (float*)dst + (b * dstCs + co0) * 65536 + y * 256 + x;
#pragma unroll
                for (int e = 0; e < 4; ++e)
                    if (co0 + e < Cout) d[e * 65536] = v[e];
            }
        }
    }
}

// ---------------- conv7 (64->27) + combine, fused ----------------
// Same compute structure as conv_mfma (nch=2, srcCs=64, mtc=2, no relu), then:
// weights -> LDS transpose (px-major, stride 33) -> per-thread KPN combine.
__global__ __launch_bounds__(256) void conv7_combine(
    const unsigned short* __restrict__ src,     // h2, NHWC 64
    const unsigned short* __restrict__ wp,      // wp7
    const float* __restrict__ bias,             // wc_b3 (27)
    const unsigned short* __restrict__ concat,  // samples at ch144..224
    float* __restrict__ res_i, float* __restrict__ outp,
    const uint4* __restrict__ zp)
{
    __shared__ char ldsraw[50688];
    uint4 (*ldsb)[1584] = (uint4(*)[1584])ldsraw;
    float* wlds = (float*)ldsraw;               // [wv][px(64)][co stride 33]
    const int tid = threadIdx.x;
    const int lane = tid & 63;
    const int wv = tid >> 6;
    const int bx = blockIdx.x, b = blockIdx.y;
    const int x0 = (bx & 3) * 64, y0 = (bx >> 2) * 4;
    const int l15 = lane & 15, l4 = lane >> 4;

    f32x4 acc[2][4];
#pragma unroll
    for (int m = 0; m < 2; ++m)
#pragma unroll
        for (int nt = 0; nt < 4; ++nt) acc[m][nt] = (f32x4)0.f;

    auto stage = [&](int buf, int chunk) {
        int ch = chunk * 32 + wv * 8;
        const unsigned short* sbase = src + ch;
#pragma unroll
        for (int it = 0; it < 7; ++it) {
            int r = it * 64 + lane;
            if (r < 396) {
                int hy = r / 66, hx = r - hy * 66;
                int y = y0 - 1 + hy, x = x0 - 1 + hx;
                const uint4* g;
                if ((unsigned)y < 256u && (unsigned)x < 256u)
                    g = (const uint4*)(sbase + (b * 65536 + y * 256 + x) * 64);
                else
                    g = zp + lane;
                __builtin_amdgcn_global_load_lds(
                    (const __attribute__((address_space(1))) void*)g,
                    (__attribute__((address_space(3))) void*)&ldsb[buf][wv * 396 + it * 64],
                    16, 0, 0);
            }
        }
    };

    stage(0, 0);
    int buf = 0;
    for (int c = 0; c < 2; ++c) {
        __syncthreads();
        if (c + 1 < 2) stage(buf ^ 1, c + 1);
#pragma unroll
        for (int tap = 0; tap < 9; ++tap) {
            const int dy = tap / 3, dx = tap - dy * 3;
            short8 af[2];
#pragma unroll
            for (int m = 0; m < 2; ++m)
                af[m] = *(const short8*)(wp +
                    ((tap * 2 + c) * 64 + m * 16 + l15) * 32 + l4 * 8);
#pragma unroll
            for (int nt = 0; nt < 4; ++nt) {
                int hx = nt * 16 + l15 + dx;
                int hy = wv + dy;
                short8 bf = __builtin_bit_cast(short8,
                    ldsb[buf][l4 * 396 + hy * 66 + hx]);
#pragma unroll
                for (int m = 0; m < 2; ++m)
                    acc[m][nt] = __builtin_amdgcn_mfma_f32_16x16x32_bf16(
                        af[m], bf, acc[m][nt], 0, 0, 0);
            }
        }
        buf ^= 1;
    }

    // ---- weights -> LDS (px-major, padded stride 33) ----
    __syncthreads();
#pragma unroll
    for (int m = 0; m < 2; ++m) {
        int co0 = m * 16 + l4 * 4;
#pragma unroll
        for (int nt = 0; nt < 4; ++nt) {
            int px = nt * 16 + l15;
#pragma unroll
            for (int e = 0; e < 4; ++e) {
                int co = co0 + e;
                wlds[wv * 2112 + px * 33 + co] =
                    acc[m][nt][e] + ((co < 27) ? bias[co] : 0.f);
            }
        }
    }
    __syncthreads();

    // ---- per-pixel combine ----
    const int r = tid >> 6, px = tid & 63;
    const float* wl = wlds + r * 2112 + px * 33;
    const int y = y0 + r, x = x0 + px;
    const int p = y * 256 + x;
    const unsigned short* cp = concat + (b * 65536 + p) * 232 + 144;
    unsigned int sw[41];
    {
        const uint4* gp = (const uint4*)cp;
#pragma unroll
        for (int k = 0; k < 10; ++k) {
            uint4 t = gp[k];
            sw[4 * k] = t.x; sw[4 * k + 1] = t.y;
            sw[4 * k + 2] = t.z; sw[4 * k + 3] = t.w;
        }
        sw[40] = (unsigned int)cp[80];
    }
    float ov[3] = {0.f, 0.f, 0.f};
#pragma unroll
    for (int g = 0; g < 3; ++g) {
        float rr[3] = {0.f, 0.f, 0.f};
#pragma unroll
        for (int k = 0; k < 9; ++k) {
            int s = g * 9 + k;
            float w = wl[s];
            int L0 = 3 * s;
            float s0 = bf2f((sw[L0 >> 1] >> ((L0 & 1) * 16)) & 0xffffu);
            float s1 = bf2f((sw[(L0 + 1) >> 1] >> (((L0 + 1) & 1) * 16)) & 0xffffu);
            float s2 = bf2f((sw[(L0 + 2) >> 1] >> (((L0 + 2) & 1) * 16)) & 0xffffu);
            rr[0] = fmaf(s0, w, rr[0]);
            rr[1] = fmaf(s1, w, rr[1]);
            rr[2] = fmaf(s2, w, rr[2]);
        }
#pragma unroll
        for (int c = 0; c < 3; ++c) {
            res_i[(b * 9 + g * 3 + c) * 65536 + p] = 3.f * rr[c];
            ov[c] += rr[c];
        }
    }
#pragma unroll
    for (int c = 0; c < 3; ++c)
        outp[(b * 3 + c) * 65536 + p] = ov[c];
}

// ---------------- trilinear: offsets -> samples, packed-texture gathers ----------------
__global__ __launch_bounds__(256) void trilin_kern(
    const unsigned short* __restrict__ dpk, unsigned short* __restrict__ concat,
    float* __restrict__ smp)
{
    int i = blockIdx.x * 256 + threadIdx.x;   // b*65536 + p
    int b = i >> 16, p = i & 65535;
    int y = p >> 8, x = p & 255;
    unsigned short* cptr = concat + i * 232 + 144;

    unsigned int wbuf[41];
    {
        const uint4* gp = (const uint4*)cptr;
#pragma unroll
        for (int k = 0; k < 10; ++k) {
            uint4 t = gp[k];
            wbuf[4 * k] = t.x; wbuf[4 * k + 1] = t.y;
            wbuf[4 * k + 2] = t.z; wbuf[4 * k + 3] = t.w;
        }
        wbuf[40] = (unsigned int)cptr[80];
    }

#pragma unroll
    for (int s = 0; s < 27; ++s) {
        int L0 = 3 * s;
        float o0 = bf2f((wbuf[L0 >> 1] >> ((L0 & 1) * 16)) & 0xffffu);
        float o1 = bf2f((wbuf[(L0 + 1) >> 1] >> (((L0 + 1) & 1) * 16)) & 0xffffu);
        float o2 = bf2f((wbuf[(L0 + 2) >> 1] >> (((L0 + 2) & 1) * 16)) & 0xffffu);

        float kd = (float)(s / 9 - 1);
        float kh = (float)((s / 3) % 3 - 1);
        float kw = (float)(s % 3 - 1);
        float pd = 2.0f + kd + o0;
        float ph = (float)y + kh + o1;
        float pw = (float)x + kw + o2;
        pd = fminf(fmaxf(pd, 0.f), 4.f);
        ph = fminf(fmaxf(ph, 0.f), 255.f);
        pw = fminf(fmaxf(pw, 0.f), 255.f);
        float d0 = floorf(pd), h0 = floorf(ph), w0 = floorf(pw);
        float fd = pd - d0, fh = ph - h0, fw = pw - w0;
        int d0i = (int)d0, h0i = (int)h0, w0i = (int)w0;
        int d1i = min(d0i + 1, 4), h1i = min(h0i + 1, 255), w1i = min(w0i + 1, 255);

        const unsigned short* p0 = dpk + (b * 5 + d0i) * 262144;
        const unsigned short* p1 = dpk + (b * 5 + d1i) * 262144;
        int a00 = ((h0i << 8) + w0i) << 2, a01 = ((h0i << 8) + w1i) << 2;
        int a10 = ((h1i << 8) + w0i) << 2, a11 = ((h1i << 8) + w1i) << 2;
        uint2 q000 = *(const uint2*)(p0 + a00), q001 = *(const uint2*)(p0 + a01);
        uint2 q010 = *(const uint2*)(p0 + a10), q011 = *(const uint2*)(p0 + a11);
        uint2 q100 = *(const uint2*)(p1 + a00), q101 = *(const uint2*)(p1 + a01);
        uint2 q110 = *(const uint2*)(p1 + a10), q111 = *(const uint2*)(p1 + a11);

        float res[3];
#pragma unroll
        for (int c = 0; c < 3; ++c) {
            auto ex = [&](uint2 q) {
                unsigned int u = (c == 0) ? (q.x & 0xffffu)
                              : (c == 1) ? (q.x >> 16) : (q.y & 0xffffu);
                return bf2f(u);
            };
            float r0 = (ex(q000) * (1.f - fw) + ex(q001) * fw) * (1.f - fh)
                     + (ex(q010) * (1.f - fw) + ex(q011) * fw) * fh;
            float r1 = (ex(q100) * (1.f - fw) + ex(q101) * fw) * (1.f - fh)
                     + (ex(q110) * (1.f - fw) + ex(q111) * fw) * fh;
            float r = r0 * (1.f - fd) + r1 * fd;
            res[c] = r;
            smp[((b * 27 + s) * 3 + c) * 65536 + p] = r;
        }
#pragma unroll
        for (int c = 0; c < 3; ++c) {
            int L = L0 + c;
            unsigned int u = (unsigned int)f2bf(res[c]);
            if (L & 1) wbuf[L >> 1] = (wbuf[L >> 1] & 0xffffu) | (u << 16);
            else       wbuf[L >> 1] = (wbuf[L >> 1] & 0xffff0000u) | u;
        }
    }

    wbuf[40] &= 0xffffu;
    uint4* gp = (uint4*)cptr;
#pragma unroll
    for (int k = 0; k < 10; ++k)
        gp[k] = make_uint4(wbuf[4 * k], wbuf[4 * k + 1], wbuf[4 * k + 2], wbuf[4 * k + 3]);
    *(unsigned int*)(cptr + 80) = wbuf[40];
}

extern "C" void kernel_launch(void* const* d_in, const int* in_sizes, int n_in,
                              void* d_out, int out_size, void* d_ws, size_t ws_size,
                              hipStream_t stream)
{
    const float* data   = (const float*)d_in[0];
    const float* enc_w1 = (const float*)d_in[1];
    const float* enc_b1 = (const float*)d_in[2];
    const float* enc_w2 = (const float*)d_in[3];
    const float* enc_b2 = (const float*)d_in[4];
    const float* off_w  = (const float*)d_in[5];
    const float* off_b  = (const float*)d_in[6];
    const float* wc_w1  = (const float*)d_in[7];
    const float* wc_b1  = (const float*)d_in[8];
    const float* wc_w2  = (const float*)d_in[9];
    const float* wc_b2  = (const float*)d_in[10];
    const float* wc_w3  = (const float*)d_in[11];
    const float* wc_b3  = (const float*)d_in[12];

    float* dout  = (float*)d_out;
    float* res_i = dout;                  // [4,3,3,256,256]
    float* outp  = dout + 2359296;        // [4,3,256,256]
    float* smp   = dout + 3145728;        // [4,27,3,256,256] fp32 NCHW

    char* ws = (char*)d_ws;
    unsigned short* concat = (unsigned short*)ws;                      // 121,634,816 B
    unsigned short* buf_a  = (unsigned short*)(ws + 121634816);        // 33,554,432 B
    unsigned short* buf_b  = (unsigned short*)(ws + 155189248);        // 33,554,432 B
    unsigned short* wpk    = (unsigned short*)(ws + 188743680);        // 921,600 B + 16 KB zp
    unsigned short* wp1 = wpk;            // 9*1*64*32  = 18432
    unsigned short* wp2 = wpk + 18432;    // 9*2*128*32 = 73728
    unsigned short* wp3 = wpk + 92160;    // 9*4*128*32 = 147456
    unsigned short* wp5 = wpk + 239616;   // 9*8*64*32  = 147456
    unsigned short* wp6 = wpk + 387072;   // 9*2*64*32  = 36864
    unsigned short* wp7 = wpk + 423936;   // 9*2*64*32  = 36864
    const uint4* zp = (const uint4*)(wpk + 460800);   // 16 KB zeros
    unsigned short* dpk = buf_b;          // packed texture; dead after trilin

    dim3 blk(256);

    prep_kern<<<1832, blk, 0, stream>>>(enc_w1, enc_w2, off_w, wc_w1, wc_w2, wc_w3, wpk);
    convert_data<<<1024, blk, 0, stream>>>(data, concat);
    pack_dpk<<<5120, blk, 0, stream>>>(data, dpk);

    // conv1: concat ch0-31 (zero-wt >=15) -> f1 (buf_a, NHWC 64)
    conv_mfma<<<dim3(256, 4, 1), blk, 0, stream>>>(
        concat, 232, 0, wp1, enc_b1, 1, 64, 64, buf_a, 64, 0, 0, 1, zp);
    // conv2: f1 -> feature (concat ch16-143)
    conv_mfma<<<dim3(256, 4, 2), blk, 0, stream>>>(
        buf_a, 64, 0, wp2, enc_b2, 2, 128, 128, concat, 232, 16, 0, 1, zp);
    // conv3: feature -> offsets (concat ch144-224)
    conv_mfma<<<dim3(256, 4, 2), blk, 0, stream>>>(
        concat, 232, 16, wp3, off_b, 4, 81, 128, concat, 232, 144, 0, 0, zp);
    // trilinear: offsets -> samples (in place in concat) + fp32 NCHW smp
    trilin_kern<<<1024, blk, 0, stream>>>(dpk, concat, smp);
    // conv5: concat 232(->256 pad) -> h1 (buf_a)
    conv_mfma<<<dim3(256, 4, 1), blk, 0, stream>>>(
        concat, 232, 0, wp5, wc_b1, 8, 64, 64, buf_a, 64, 0, 0, 1, zp);
    // conv6: h1 -> h2 (buf_b; overwrites dpk, which is dead now)
    conv_mfma<<<dim3(256, 4, 1), blk, 0, stream>>>(
        buf_a, 64, 0, wp6, wc_b2, 2, 64, 64, buf_b, 64, 0, 0, 1, zp);
    // conv7 + combine fused
    conv7_combine<<<dim3(256, 4), blk, 0, stream>>>(
        buf_b, wp7, wc_b3, concat, res_i, outp, zp);
}